// Round 6
// baseline (45.124 us; speedup 1.0000x reference)
//
#include <hip/hip_runtime.h>
#include <hip/hip_bf16.h>
#include <math.h>

#define HH 768
#define NB 8
#define LL 256
#define MM 128
#define NROW1 (NB*MM)        // 1024 dns rows
#define NROW2 (NB*LL)        // 2048 text rows
#define NROWS (NROW1+NROW2)  // 3072
#define NCB 12               // 768/64 column blocks

typedef __attribute__((ext_vector_type(8)))  short bf16x8;
typedef __attribute__((ext_vector_type(16))) float f32x16;

static __device__ __forceinline__ unsigned int pkbf2(float a, float b) {
    __hip_bfloat162 h = __float22bfloat162_rn(make_float2(a, b));
    unsigned int u; __builtin_memcpy(&u, &h, 4); return u;
}

static __device__ __forceinline__ float fast_tanh(float x) {
    float e = __expf(2.0f * x);
    return 1.0f - 2.0f * __builtin_amdgcn_rcpf(e + 1.0f);
}

// ---------------------------------------------------------------------------
// One-shot fp32 -> bf16 conversion of all GEMM operands.
// ---------------------------------------------------------------------------
__global__ __launch_bounds__(256) void prep_bf16(
    const float4* __restrict__ text, const float4* __restrict__ dns,
    const float4* __restrict__ Wd1, const float4* __restrict__ Wt2,
    uint2* __restrict__ Xb, uint2* __restrict__ Wb)
{
    const int i = blockIdx.x * 256 + threadIdx.x;   // 884736 threads exactly
    const float4* src; uint2* dst;
    if (i < 589824) {
        dst = Xb + i;
        src = (i < 196608) ? (dns + i) : (text + (i - 196608));
    } else {
        dst = Wb + (i - 589824);
        src = (i < 737280) ? (Wd1 + (i - 589824)) : (Wt2 + (i - 737280));
    }
    float4 v = *src;
    uint2 o; o.x = pkbf2(v.x, v.y); o.y = pkbf2(v.z, v.w);
    *dst = o;
}

// ---------------------------------------------------------------------------
// LDS-free score GEMM: 1 wave/block, 64 rows x 64 cols, mfma_32x32x16_bf16.
// A/B fragments are 8 contiguous-in-K bf16 per lane (row/col = lane&31,
// k-off = (lane>>5)*8) -> direct uint4 global loads from L2-hot Xb/Wb.
// No LDS, no barriers. acc[rowgroup][colgroup] = 2x2 x f32x16.
// Epilogue: tanh * wvec, 5x shfl_xor reduce over the 32 col-lanes,
// C/D layout: col=lane&31, row=(reg&3)+8*(reg>>2)+4*(lane>>5).
// Grid 576 = 48 rowblocks x 12 colblocks, XCD-chunked swizzle (576 = 8*72).
// ---------------------------------------------------------------------------
__global__ __launch_bounds__(64, 2) void score_direct(
    const unsigned short* __restrict__ Xb, const unsigned short* __restrict__ Wb,
    const float* __restrict__ wv1, const float* __restrict__ wv2,
    float* __restrict__ partial)
{
    const int l = threadIdx.x;
    const int tile = (blockIdx.x >> 3) + (blockIdx.x & 7) * 72;  // bijective
    const int rb = tile / 12, cb = tile % 12;
    const int row0 = rb * 64, col0 = cb * 64;

    const unsigned short* W; const float* wv;
    if (row0 < NROW1) { W = Wb;                   wv = wv1; }
    else              { W = Wb + (size_t)HH * HH; wv = wv2; }

    const int lr = l & 31;
    const int lk = (l >> 5) * 8;
    const unsigned short* xp = Xb + (size_t)(row0 + lr) * HH + lk;
    const unsigned short* wp = W  + (size_t)(col0 + lr) * HH + lk;

    f32x16 acc[2][2] = {};
    uint4 a0[2][2], b0[2][2], a1[2][2], b1[2][2];

    auto LOAD = [&](uint4 (&a)[2][2], uint4 (&b)[2][2], int k0) {
        #pragma unroll
        for (int g = 0; g < 2; ++g) {
            #pragma unroll
            for (int s = 0; s < 2; ++s) {
                a[g][s] = *(const uint4*)(xp + (size_t)g * 32 * HH + k0 + s * 16);
                b[g][s] = *(const uint4*)(wp + (size_t)g * 32 * HH + k0 + s * 16);
            }
        }
    };
    auto MF = [&](uint4 (&a)[2][2], uint4 (&b)[2][2]) {
        #pragma unroll
        for (int s = 0; s < 2; ++s)
            #pragma unroll
            for (int rg = 0; rg < 2; ++rg)
                #pragma unroll
                for (int cg = 0; cg < 2; ++cg)
                    acc[rg][cg] = __builtin_amdgcn_mfma_f32_32x32x16_bf16(
                        *(const bf16x8*)&a[rg][s], *(const bf16x8*)&b[cg][s],
                        acc[rg][cg], 0, 0, 0);
    };

    LOAD(a0, b0, 0);
    #pragma unroll 1
    for (int k0 = 0; k0 < HH; k0 += 64) {          // 12 iterations of 2x32
        LOAD(a1, b1, k0 + 32);
        MF(a0, b0);
        if (k0 + 64 < HH) LOAD(a0, b0, k0 + 64);
        MF(a1, b1);
    }

    // epilogue
    const float wva = wv[col0 + lr];
    const float wvb = wv[col0 + 32 + lr];
    #pragma unroll
    for (int rg = 0; rg < 2; ++rg) {
        #pragma unroll
        for (int r = 0; r < 16; ++r) {
            float v = fast_tanh(acc[rg][0][r]) * wva + fast_tanh(acc[rg][1][r]) * wvb;
            v += __shfl_xor(v, 1);
            v += __shfl_xor(v, 2);
            v += __shfl_xor(v, 4);
            v += __shfl_xor(v, 8);
            v += __shfl_xor(v, 16);
            if (lr == 0) {
                const int row = row0 + rg * 32 + (r & 3) + 8 * (r >> 2) + 4 * (l >> 5);
                partial[(size_t)row * NCB + cb] = v;
            }
        }
    }
}

// ---------------------------------------------------------------------------
// Fused softmax + weighted-sum slice. Grid (8 b, 6 hc, 8 rs), 256 threads.
// Each block recomputes its batch's softmax from L2-hot partials (proven
// round-4 finish code), then accumulates its 1/8 slice of the weighted sums.
// ---------------------------------------------------------------------------
__global__ __launch_bounds__(256) void wsum_sm(
    const float* __restrict__ text, const float* __restrict__ dns,
    const float* __restrict__ partial, float* __restrict__ pvt, float* __restrict__ pvd)
{
    const int b = blockIdx.x, hc = blockIdx.y, rs = blockIdx.z;
    const int t = threadIdx.x;
    __shared__ float p1s[128], p2s[256], red[8], bt[256], bd[256];

    if (t < 128) {
        const float* pr = partial + (size_t)(b * MM + t) * NCB;
        float s = 0.f;
        #pragma unroll
        for (int c = 0; c < NCB; ++c) s += pr[c];
        p1s[t] = s;
    }
    {
        const float* pr = partial + (size_t)(NROW1 + b * LL + t) * NCB;
        float s = 0.f;
        #pragma unroll
        for (int c = 0; c < NCB; ++c) s += pr[c];
        p2s[t] = s;
    }
    __syncthreads();

    float x1 = (t < 128) ? p1s[t] : -1e30f;
    float m1 = x1;
    #pragma unroll
    for (int d = 1; d < 64; d <<= 1) m1 = fmaxf(m1, __shfl_xor(m1, d));
    if ((t & 63) == 0) red[t >> 6] = m1;
    float x2 = p2s[t];
    float m2 = x2;
    #pragma unroll
    for (int d = 1; d < 64; d <<= 1) m2 = fmaxf(m2, __shfl_xor(m2, d));
    if ((t & 63) == 0) red[4 + (t >> 6)] = m2;
    __syncthreads();
    m1 = fmaxf(fmaxf(red[0], red[1]), fmaxf(red[2], red[3]));
    m2 = fmaxf(fmaxf(red[4], red[5]), fmaxf(red[6], red[7]));

    float e1 = (t < 128) ? __expf(x1 - m1) : 0.f;
    float e2 = __expf(x2 - m2);
    __syncthreads();
    float s1 = e1, s2 = e2;
    #pragma unroll
    for (int d = 1; d < 64; d <<= 1) { s1 += __shfl_xor(s1, d); s2 += __shfl_xor(s2, d); }
    if ((t & 63) == 0) { red[t >> 6] = s1; red[4 + (t >> 6)] = s2; }
    __syncthreads();
    s1 = red[0] + red[1] + red[2] + red[3];
    s2 = red[4] + red[5] + red[6] + red[7];
    if (t < 128) p1s[t] = e1 / s1;
    p2s[t] = e2 / s2;
    __syncthreads();

    const int h = hc * 128 + (t & 127);
    const int sub = t >> 7;

    const int jr0 = rs * 32 + sub * 16;          // 16 text rows
    float st = 0.f;
    #pragma unroll
    for (int r = 0; r < 16; ++r)
        st = fmaf(p2s[jr0 + r], text[(size_t)(b * LL + jr0 + r) * HH + h], st);

    const int mr0 = rs * 16 + sub * 8;           // 8 dns rows
    float sd = 0.f;
    #pragma unroll
    for (int r = 0; r < 8; ++r)
        sd = fmaf(p1s[mr0 + r], dns[(size_t)(b * MM + mr0 + r) * HH + h], sd);

    bt[t] = st; bd[t] = sd;
    __syncthreads();
    if (sub == 0) {
        pvt[(size_t)(rs * NB + b) * HH + h] = bt[t] + bt[t + 128];
        pvd[(size_t)(rs * NB + b) * HH + h] = bd[t] + bd[t + 128];
    }
}

// ---------------------------------------------------------------------------
// Sum the 8 partials (L2-hot) and broadcast-write both outputs.
// 256 blocks = 8 b x 32 L-chunks (8 rows each).
// ---------------------------------------------------------------------------
__global__ __launch_bounds__(256) void bcast_reduce(
    const float4* __restrict__ pvt4, const float4* __restrict__ pvd4,
    float4* __restrict__ out)
{
    const int b = blockIdx.x >> 5;
    const int l0 = (blockIdx.x & 31) * 8;
    const int t = threadIdx.x;
    const int H4 = HH / 4;                       // 192
    const int n4out = NB * LL * H4;              // 393216

    __shared__ float4 svt[192], svd[192];
    if (t < 192) {
        float4 a = make_float4(0.f, 0.f, 0.f, 0.f);
        float4 c = make_float4(0.f, 0.f, 0.f, 0.f);
        #pragma unroll
        for (int s = 0; s < 8; ++s) {
            float4 u = pvt4[(size_t)(s * NB + b) * H4 + t];
            float4 v = pvd4[(size_t)(s * NB + b) * H4 + t];
            a.x += u.x; a.y += u.y; a.z += u.z; a.w += u.w;
            c.x += v.x; c.y += v.y; c.z += v.z; c.w += v.w;
        }
        svt[t] = a; svd[t] = c;
    }
    __syncthreads();

    #pragma unroll
    for (int i = t; i < 1536; i += 256) {        // 8 rows x 192 f4
        const int row = i / 192, h4 = i % 192;
        const int ll = l0 + row;
        out[(size_t)(b * LL + ll) * H4 + h4] = svt[h4];
        out[n4out + (size_t)(b * LL + ll) * H4 + h4] = svd[h4];
    }
}

extern "C" void kernel_launch(void* const* d_in, const int* in_sizes, int n_in,
                              void* d_out, int out_size, void* d_ws, size_t ws_size,
                              hipStream_t stream) {
    const float* text   = (const float*)d_in[0];   // (8,256,768)
    const float* dns    = (const float*)d_in[1];   // (8,128,768)
    const float* W_d1   = (const float*)d_in[4];   // (768,768)
    const float* w_att1 = (const float*)d_in[5];   // (1536,)
    const float* W_t2   = (const float*)d_in[9];   // (768,768)
    const float* w_att2 = (const float*)d_in[10];  // (1536,)

    float* ws      = (float*)d_ws;
    float* partial = ws;                                   // 36864 f
    float* pvt     = ws + 36864;                           // 49152
    float* pvd     = ws + 86016;                           // 49152
    unsigned short* Xb = (unsigned short*)(ws + 135168);   // 2359296 bf16
    unsigned short* Wb = Xb + (size_t)NROWS * HH;          // 1179648 bf16
    float* out     = (float*)d_out;

    prep_bf16<<<3456, 256, 0, stream>>>(
        (const float4*)text, (const float4*)dns, (const float4*)W_d1,
        (const float4*)W_t2, (uint2*)Xb, (uint2*)Wb);
    score_direct<<<576, 64, 0, stream>>>(
        Xb, Wb, w_att1 + HH, w_att2 + HH, partial);
    wsum_sm<<<dim3(NB, 6, 8), 256, 0, stream>>>(text, dns, partial, pvt, pvd);
    bcast_reduce<<<256, 256, 0, stream>>>(
        (const float4*)pvt, (const float4*)pvd, (float4*)out);
}

// Round 7
// 30.708 us; speedup vs baseline: 1.4695x; 1.4695x over previous
//
#include <hip/hip_runtime.h>
#include <hip/hip_bf16.h>
#include <math.h>

#define HH 768
#define NB 8
#define LL 256
#define MM 128
#define NROW1 (NB*MM)        // 1024 dns rows
#define NROW2 (NB*LL)        // 2048 text rows
#define NROWS (NROW1+NROW2)  // 3072
#define NCB 12               // 768/64 column blocks

typedef __attribute__((ext_vector_type(8))) short  bf16x8;
typedef __attribute__((ext_vector_type(4))) float  f32x4;

static __device__ __forceinline__ unsigned int pkbf2(float a, float b) {
    __hip_bfloat162 h = __float22bfloat162_rn(make_float2(a, b));
    unsigned int u; __builtin_memcpy(&u, &h, 4); return u;
}

static __device__ __forceinline__ float fast_tanh(float x) {
    float e = __expf(2.0f * x);
    return 1.0f - 2.0f * __builtin_amdgcn_rcpf(e + 1.0f);
}

// ---------------------------------------------------------------------------
// One-shot fp32 -> bf16 conversion of all GEMM operands. (proven r4-6)
// ---------------------------------------------------------------------------
__global__ __launch_bounds__(256) void prep_bf16(
    const float4* __restrict__ text, const float4* __restrict__ dns,
    const float4* __restrict__ Wd1, const float4* __restrict__ Wt2,
    uint2* __restrict__ Xb, uint2* __restrict__ Wb)
{
    const int i = blockIdx.x * 256 + threadIdx.x;   // 884736 threads exactly
    const float4* src; uint2* dst;
    if (i < 589824) {
        dst = Xb + i;
        src = (i < 196608) ? (dns + i) : (text + (i - 196608));
    } else {
        dst = Wb + (i - 589824);
        src = (i < 737280) ? (Wd1 + (i - 589824)) : (Wt2 + (i - 737280));
    }
    float4 v = *src;
    uint2 o; o.x = pkbf2(v.x, v.y); o.y = pkbf2(v.z, v.w);
    *dst = o;
}

// ---------------------------------------------------------------------------
// bf16-MFMA GEMM + tanh + dot (both score GEMMs). Verbatim round-5 (proven:
// 4 waves/block, 2304 waves total -- the TLP that round-6's 1-wave variant
// lost). Tile 64x64, BK=64; wave w owns rows [w*16,w*16+16) x all 64 cols.
// ---------------------------------------------------------------------------
__global__ __launch_bounds__(256) void score_mfma(
    const unsigned short* __restrict__ Xb, const unsigned short* __restrict__ Wb,
    const float* __restrict__ wv1, const float* __restrict__ wv2,
    float* __restrict__ partial)
{
    __shared__ __align__(16) unsigned short As[64][72];
    __shared__ __align__(16) unsigned short Bs[64][72];

    const int t = threadIdx.x;
    const int tile = (blockIdx.x >> 3) + (blockIdx.x & 7) * 72;  // 576 = 8*72
    const int rb = tile / 12, cb = tile % 12;
    const int row0 = rb * 64, col0 = cb * 64;

    const unsigned short* X = Xb + (size_t)row0 * HH;
    const unsigned short* W; const float* wv;
    if (row0 < NROW1) { W = Wb;                    wv = wv1; }
    else              { W = Wb + (size_t)HH * HH;  wv = wv2; }

    const int sr = t >> 2;
    const int c4 = t & 3;
    const unsigned short* xp = X + (size_t)sr * HH + c4 * 16;
    const unsigned short* wp = W + (size_t)(col0 + sr) * HH + c4 * 16;

    const int l  = t & 63;
    const int w  = t >> 6;
    const int wr = w * 16;
    const int lc = l & 15;
    const int lk = (l >> 4) * 8;

    f32x4 acc[4] = {};
    uint4 rA0, rA1, rB0, rB1, nA0, nA1, nB0, nB1;

    auto STAGE = [&]() {
        *reinterpret_cast<uint4*>(&As[sr][c4 * 16    ]) = rA0;
        *reinterpret_cast<uint4*>(&As[sr][c4 * 16 + 8]) = rA1;
        *reinterpret_cast<uint4*>(&Bs[sr][c4 * 16    ]) = rB0;
        *reinterpret_cast<uint4*>(&Bs[sr][c4 * 16 + 8]) = rB1;
    };
    auto MFMA_TILE = [&]() {
        #pragma unroll
        for (int kk = 0; kk < 2; ++kk) {
            const int ko = kk * 32 + lk;
            bf16x8 a = *reinterpret_cast<const bf16x8*>(&As[wr + lc][ko]);
            #pragma unroll
            for (int n = 0; n < 4; ++n) {
                bf16x8 b = *reinterpret_cast<const bf16x8*>(&Bs[n*16 + lc][ko]);
                acc[n] = __builtin_amdgcn_mfma_f32_16x16x32_bf16(a, b, acc[n], 0, 0, 0);
            }
        }
    };

    rA0 = *(const uint4*)(xp);     rA1 = *(const uint4*)(xp + 8);
    rB0 = *(const uint4*)(wp);     rB1 = *(const uint4*)(wp + 8);

    #pragma unroll 1
    for (int k0 = 0; k0 < HH - 64; k0 += 64) {
        STAGE();
        __syncthreads();
        nA0 = *(const uint4*)(xp + k0 + 64);  nA1 = *(const uint4*)(xp + k0 + 72);
        nB0 = *(const uint4*)(wp + k0 + 64);  nB1 = *(const uint4*)(wp + k0 + 72);
        MFMA_TILE();
        __syncthreads();
        rA0 = nA0; rA1 = nA1; rB0 = nB0; rB1 = nB1;
    }
    STAGE();
    __syncthreads();
    MFMA_TILE();

    float wvn[4];
    #pragma unroll
    for (int n = 0; n < 4; ++n) wvn[n] = wv[col0 + n*16 + lc];
    #pragma unroll
    for (int i = 0; i < 4; ++i) {
        float s = 0.f;
        #pragma unroll
        for (int n = 0; n < 4; ++n) s += fast_tanh(acc[n][i]) * wvn[n];
        s += __shfl_xor(s, 1);
        s += __shfl_xor(s, 2);
        s += __shfl_xor(s, 4);
        s += __shfl_xor(s, 8);
        if (lc == 0)
            partial[(size_t)(row0 + wr + (l >> 4)*4 + i) * NCB + cb] = s;
    }
}

// ---------------------------------------------------------------------------
// Fully fused tail: per (batch, 16-h-column stripe) block recomputes the
// batch softmax from L2-hot partials (verbatim proven r6 code), computes the
// weighted sums for its 16 h-columns via 16 row-slices + LDS tree, then
// broadcast-writes its stripe of BOTH outputs. Grid (8, 48), 256 threads.
// ---------------------------------------------------------------------------
__global__ __launch_bounds__(256) void tail_kernel(
    const float* __restrict__ text, const float* __restrict__ dns,
    const float* __restrict__ partial, float* __restrict__ out)
{
    const int b = blockIdx.x, hc = blockIdx.y;   // hc 0..47
    const int t = threadIdx.x;
    __shared__ float p1s[128], p2s[256], red[8];
    __shared__ __align__(16) float bt[256], bd[256];

    // --- per-row partial reduction (12 col-blocks) ---
    if (t < 128) {
        const float* pr = partial + (size_t)(b * MM + t) * NCB;
        float s = 0.f;
        #pragma unroll
        for (int c = 0; c < NCB; ++c) s += pr[c];
        p1s[t] = s;
    }
    {
        const float* pr = partial + (size_t)(NROW1 + b * LL + t) * NCB;
        float s = 0.f;
        #pragma unroll
        for (int c = 0; c < NCB; ++c) s += pr[c];
        p2s[t] = s;
    }
    __syncthreads();

    // --- softmax over p1 (128) and p2 (256), proven code ---
    float x1 = (t < 128) ? p1s[t] : -1e30f;
    float m1 = x1;
    #pragma unroll
    for (int d = 1; d < 64; d <<= 1) m1 = fmaxf(m1, __shfl_xor(m1, d));
    if ((t & 63) == 0) red[t >> 6] = m1;
    float x2 = p2s[t];
    float m2 = x2;
    #pragma unroll
    for (int d = 1; d < 64; d <<= 1) m2 = fmaxf(m2, __shfl_xor(m2, d));
    if ((t & 63) == 0) red[4 + (t >> 6)] = m2;
    __syncthreads();
    m1 = fmaxf(fmaxf(red[0], red[1]), fmaxf(red[2], red[3]));
    m2 = fmaxf(fmaxf(red[4], red[5]), fmaxf(red[6], red[7]));

    float e1 = (t < 128) ? __expf(x1 - m1) : 0.f;
    float e2 = __expf(x2 - m2);
    __syncthreads();
    float s1 = e1, s2 = e2;
    #pragma unroll
    for (int d = 1; d < 64; d <<= 1) { s1 += __shfl_xor(s1, d); s2 += __shfl_xor(s2, d); }
    if ((t & 63) == 0) { red[t >> 6] = s1; red[4 + (t >> 6)] = s2; }
    __syncthreads();
    s1 = red[0] + red[1] + red[2] + red[3];
    s2 = red[4] + red[5] + red[6] + red[7];
    if (t < 128) p1s[t] = e1 / s1;
    p2s[t] = e2 / s2;
    __syncthreads();

    // --- weighted sums for this block's 16 h-columns ---
    const int hh  = hc * 16 + (t & 15);
    const int rsl = t >> 4;                      // 0..15 row-slices

    const int jr0 = rsl * 16;                    // 16 text rows per slice
    float st = 0.f;
    #pragma unroll
    for (int r = 0; r < 16; ++r)
        st = fmaf(p2s[jr0 + r], text[(size_t)(b * LL + jr0 + r) * HH + hh], st);

    const int mr0 = rsl * 8;                     // 8 dns rows per slice
    float sd = 0.f;
    #pragma unroll
    for (int r = 0; r < 8; ++r)
        sd = fmaf(p1s[mr0 + r], dns[(size_t)(b * MM + mr0 + r) * HH + hh], sd);

    bt[t] = st; bd[t] = sd;
    __syncthreads();
    if (t < 128) { bt[t] += bt[t + 128]; bd[t] += bd[t + 128]; } __syncthreads();
    if (t < 64)  { bt[t] += bt[t + 64];  bd[t] += bd[t + 64];  } __syncthreads();
    if (t < 32)  { bt[t] += bt[t + 32];  bd[t] += bd[t + 32];  } __syncthreads();
    if (t < 16)  { bt[t] += bt[t + 16];  bd[t] += bd[t + 16];  }
    __syncthreads();
    // bt[0..15] = att_text vec for hh=hc*16+0..15 ; bd[0..15] = att_dns vec

    // --- broadcast-write this stripe of both outputs ---
    const int H4 = HH / 4;                       // 192
    const int n4out = NB * LL * H4;              // 393216
    const float4* svt4 = reinterpret_cast<const float4*>(bt);  // 4 float4
    const float4* svd4 = reinterpret_cast<const float4*>(bd);
    float4* out4 = reinterpret_cast<float4*>(out);
    #pragma unroll
    for (int i = t; i < LL * 4; i += 256) {      // 1024 = 256 rows x 4 f4
        const int ll = i >> 2, c4 = i & 3;
        const size_t o = (size_t)(b * LL + ll) * H4 + hc * 4 + c4;
        out4[o] = svt4[c4];
        out4[n4out + o] = svd4[c4];
    }
}

extern "C" void kernel_launch(void* const* d_in, const int* in_sizes, int n_in,
                              void* d_out, int out_size, void* d_ws, size_t ws_size,
                              hipStream_t stream) {
    const float* text   = (const float*)d_in[0];   // (8,256,768)
    const float* dns    = (const float*)d_in[1];   // (8,128,768)
    const float* W_d1   = (const float*)d_in[4];   // (768,768)
    const float* w_att1 = (const float*)d_in[5];   // (1536,)
    const float* W_t2   = (const float*)d_in[9];   // (768,768)
    const float* w_att2 = (const float*)d_in[10];  // (1536,)

    float* ws      = (float*)d_ws;
    float* partial = ws;                                   // 36864 f
    unsigned short* Xb = (unsigned short*)(ws + 36864);    // 2359296 bf16
    unsigned short* Wb = Xb + (size_t)NROWS * HH;          // 1179648 bf16
    float* out     = (float*)d_out;

    prep_bf16<<<3456, 256, 0, stream>>>(
        (const float4*)text, (const float4*)dns, (const float4*)W_d1,
        (const float4*)W_t2, (uint2*)Xb, (uint2*)Wb);
    score_mfma<<<576, 256, 0, stream>>>(
        Xb, Wb, w_att1 + HH, w_att2 + HH, partial);
    tail_kernel<<<dim3(NB, 48), 256, 0, stream>>>(text, dns, partial, out);
}